// Round 2
// baseline (466.237 us; speedup 1.0000x reference)
//
#include <hip/hip_runtime.h>

#define N_ 128
#define C_ 64
#define O_ 64
#define R_ 8
#define T_ 128
#define V_ 25
#define TV_ 3200   // T_*V_
#define EPS_ 1e-5f
#define G_ 4       // c-group per block in k5

// ---------------- Kernel A: fused x3 + x12 partials + V-pool ----------------
// grid 1280 (=N*10), block 320.  Each block owns 320 consecutive p=(t,v) points of one n.
//  x3[n,r,p]     = b5[r] + sum_i w5[r,i]*x[n,i,p]           (written to global)
//  ppool[n,r,t] += sum_{v in block} x3[n,r,t,v]             (global atomics, needs memset)
//  x12p[n,blk,s,r,v] = sum_i w_s[r,i] * sum_{t in block} x[n,i,t,v]   (no atomics)
__global__ __launch_bounds__(320) void kA(const float* __restrict__ x,
        const float* __restrict__ w5, const float* __restrict__ b5,
        const float* __restrict__ w1, const float* __restrict__ w2,
        float* __restrict__ x3, float* __restrict__ x12p, float* __restrict__ ppool) {
    int blk = blockIdx.x;
    int n = blk / 10, bin_n = blk % 10;
    int tid = threadIdx.x;
    int p = bin_n * 320 + tid;                 // < 3200 always
    int t = p / V_, v = p % V_;
    int t0 = (bin_n * 320) / V_;               // first t this block touches
    __shared__ float xbins[C_ * V_];           // 1600: sum over block's t of x[n,i,t,v]
    __shared__ float pbins[R_][16];            // t-local V-pool partials
    __shared__ float w5s[R_ * C_];
    __shared__ float w12s[2 * R_ * C_];
    for (int idx = tid; idx < C_ * V_; idx += 320) xbins[idx] = 0.f;
    if (tid < R_ * 16) pbins[tid / 16][tid % 16] = 0.f;
    for (int idx = tid; idx < R_ * C_; idx += 320) w5s[idx] = w5[idx];
    for (int idx = tid; idx < 2 * R_ * C_; idx += 320)
        w12s[idx] = (idx < R_ * C_) ? w1[idx] : w2[idx - R_ * C_];
    __syncthreads();

    float acc[R_];
    #pragma unroll
    for (int r = 0; r < R_; ++r) acc[r] = b5[r];
    const float* xp = x + (size_t)n * C_ * TV_ + p;
    for (int i = 0; i < C_; ++i) {
        float xv = xp[(size_t)i * TV_];
        atomicAdd(&xbins[i * V_ + v], xv);
        #pragma unroll
        for (int r = 0; r < R_; ++r) acc[r] += w5s[r * C_ + i] * xv;
    }
    float* x3p = x3 + (size_t)n * R_ * TV_ + p;
    #pragma unroll
    for (int r = 0; r < R_; ++r) {
        x3p[(size_t)r * TV_] = acc[r];
        atomicAdd(&pbins[r][t - t0], acc[r]);
    }
    __syncthreads();
    // flush V-pool partials (max t-span per block is 14 < 16)
    if (tid < R_ * 16) {
        int r = tid / 16, tc = tid % 16;
        int tt = t0 + tc;
        if (tt < T_) atomicAdd(&ppool[((size_t)n * R_ + r) * T_ + tt], pbins[r][tc]);
    }
    // x12 partials: s in {0,1} selects w1/w2
    for (int idx = tid; idx < 2 * R_ * V_; idx += 320) {
        int s = idx / (R_ * V_), rv = idx % (R_ * V_);
        int r = rv / V_, vv = rv % V_;
        const float* wrow = &w12s[s * R_ * C_ + r * C_];
        float a = 0.f;
        for (int i = 0; i < C_; ++i) a += wrow[i] * xbins[i * V_ + vv];
        x12p[((size_t)(n * 10 + bin_n) * 2 + s) * (R_ * V_) + rv] = a;
    }
}

// ---------------- K2: x12 partials -> rel2[n,o,u,v] ----------------
// grid (N, 4), block 256; each block does 16 output channels.
__global__ __launch_bounds__(256) void k2_rel(const float* __restrict__ x12p,
        const float* __restrict__ b1, const float* __restrict__ b2,
        const float* __restrict__ w4, const float* __restrict__ b4,
        const float* __restrict__ A, const float* __restrict__ alpha,
        float* __restrict__ rel2) {
    int n = blockIdx.x, og = blockIdx.y;
    int c0 = og * 16;
    int tid = threadIdx.x;
    __shared__ float x1s[R_ * V_];
    __shared__ float x2s[R_ * V_];
    __shared__ float rels[R_ * 625];
    const float invT = 1.0f / (float)T_;
    for (int idx = tid; idx < 2 * R_ * V_; idx += 256) {
        int s = idx / (R_ * V_), rv = idx % (R_ * V_);
        float a = 0.f;
        for (int b = 0; b < 10; ++b)
            a += x12p[((size_t)(n * 10 + b) * 2 + s) * (R_ * V_) + rv];
        a = a * invT + (s ? b2[rv / V_] : b1[rv / V_]);
        (s ? x2s : x1s)[rv] = a;
    }
    __syncthreads();
    for (int idx = tid; idx < R_ * 625; idx += 256) {
        int r = idx / 625, uv = idx % 625;
        rels[idx] = tanhf(x1s[r * V_ + uv / V_] - x2s[r * V_ + uv % V_]);
    }
    __syncthreads();
    float al = alpha[0];
    for (int idx = tid; idx < 16 * 625; idx += 256) {
        int o = c0 + idx / 625, uv = idx % 625;
        float acc = b4[o];
        #pragma unroll
        for (int r = 0; r < R_; ++r) acc += w4[o * R_ + r] * rels[r * 625 + uv];
        rel2[((size_t)n * O_ + o) * 625 + uv] = acc * al + A[uv];
    }
}

// ---------------- K4: RouteFuncMLP -> rf[n,r,t] (reads pooled tensor) ----------------
__global__ __launch_bounds__(256) void k4_route(const float* __restrict__ ppool,
        const float* __restrict__ g_w, const float* __restrict__ g_b,
        const float* __restrict__ a_w, const float* __restrict__ a_b,
        const float* __restrict__ bn_g, const float* __restrict__ bn_b,
        const float* __restrict__ bn_rm, const float* __restrict__ bn_rv,
        const float* __restrict__ rf_bw, float* __restrict__ rf) {
    int n = blockIdx.x, tid = threadIdx.x;
    __shared__ float ps[R_][T_];
    __shared__ float hs[R_][T_];
    __shared__ float gs[R_];
    __shared__ float ggs[R_];
    for (int idx = tid; idx < R_ * T_; idx += 256)
        ps[idx / T_][idx % T_] = ppool[(size_t)n * R_ * T_ + idx] * (1.0f / V_);
    __syncthreads();
    if (tid < R_) {
        float s = 0.f;
        for (int t = 0; t < T_; ++t) s += ps[tid][t];
        gs[tid] = s * (1.0f / T_);
    }
    __syncthreads();
    if (tid < R_) {
        float a = g_b[tid];
        #pragma unroll
        for (int i = 0; i < R_; ++i) a += g_w[tid * R_ + i] * gs[i];
        ggs[tid] = a;
    }
    __syncthreads();
    for (int idx = tid; idx < R_ * T_; idx += 256) {
        int r = idx / T_, t = idx % T_;
        float acc = a_b[r];
        #pragma unroll
        for (int i = 0; i < R_; ++i) {
            #pragma unroll
            for (int k = 0; k < 3; ++k) {
                int tt = t + k - 1;
                if (tt >= 0 && tt < T_)
                    acc += a_w[(r * R_ + i) * 3 + k] * (ps[i][tt] + ggs[i]);
            }
        }
        float sc = bn_g[r] * rsqrtf(bn_rv[r] + EPS_);
        float h = (acc - bn_rm[r]) * sc + bn_b[r];
        hs[r][t] = fmaxf(h, 0.f);
    }
    __syncthreads();
    for (int idx = tid; idx < R_ * T_; idx += 256) {
        int r = idx / T_, t = idx % T_;
        float acc = 1.0f;
        #pragma unroll
        for (int i = 0; i < R_; ++i) {
            #pragma unroll
            for (int k = 0; k < 3; ++k) {
                int tt = t + k - 1;
                if (tt >= 0 && tt < T_)
                    acc += rf_bw[(r * R_ + i) * 3 + k] * hs[i][tt];
            }
        }
        rf[((size_t)n * R_ + r) * T_ + t] = acc;
    }
}

// ---------------- K5: out[n,c,t,u] = sum_v rel2[n,c,u,v] * z[n,c,t,v] ----------------
// grid N*16*2 (c-group of 4, t-half), block 256.
__global__ __launch_bounds__(256) void k5_out(const float* __restrict__ x3,
        const float* __restrict__ rf, const float* __restrict__ rel2,
        const float* __restrict__ w3, const float* __restrict__ b3,
        float* __restrict__ out) {
    int b = blockIdx.x;
    int n = b / 32;
    int rem = b % 32;
    int cg = rem / 2, th = rem % 2;
    int c0 = cg * G_;
    int tid = threadIdx.x;
    __shared__ float rfs[R_][T_ / 2];          // 2 KB
    __shared__ float zs[G_][1600];             // 25.6 KB
    __shared__ float rels[G_][625];            // 10 KB
    for (int idx = tid; idx < R_ * (T_ / 2); idx += 256) {
        int r = idx / (T_ / 2), tt = idx % (T_ / 2);
        rfs[r][tt] = rf[((size_t)n * R_ + r) * T_ + th * (T_ / 2) + tt];
    }
    for (int idx = tid; idx < G_ * 625; idx += 256)
        rels[idx / 625][idx % 625] = rel2[((size_t)n * O_ + c0 + idx / 625) * 625 + idx % 625];
    float w3s[G_][R_], b3s[G_];
    #pragma unroll
    for (int cl = 0; cl < G_; ++cl) {
        b3s[cl] = b3[c0 + cl];
        #pragma unroll
        for (int r = 0; r < R_; ++r) w3s[cl][r] = w3[(c0 + cl) * R_ + r];
    }
    __syncthreads();
    // phase A: z for this (c-group, t-half)
    const float* x3p = x3 + (size_t)n * R_ * TV_ + th * 1600;
    for (int p = tid; p < 1600; p += 256) {
        int t = p / V_;
        float xv[R_];
        #pragma unroll
        for (int r = 0; r < R_; ++r) xv[r] = x3p[(size_t)r * TV_ + p] * rfs[r][t];
        #pragma unroll
        for (int cl = 0; cl < G_; ++cl) {
            float acc = b3s[cl];
            #pragma unroll
            for (int r = 0; r < R_; ++r) acc += w3s[cl][r] * xv[r];
            zs[cl][p] = acc;
        }
    }
    __syncthreads();
    // phase B: idx=(t,u), all 256 threads, coalesced stores
    float* op = out + (((size_t)n * O_ + c0) * T_ + th * (T_ / 2)) * V_;
    for (int cl = 0; cl < G_; ++cl) {
        const float* zrow = zs[cl];
        const float* rrow = rels[cl];
        for (int idx = tid; idx < 1600; idx += 256) {
            int t = idx / V_, u = idx % V_;
            float acc = 0.f;
            #pragma unroll
            for (int v = 0; v < V_; ++v) acc += zrow[t * V_ + v] * rrow[u * V_ + v];
            op[(size_t)cl * T_ * V_ + idx] = acc;
        }
    }
}

extern "C" void kernel_launch(void* const* d_in, const int* in_sizes, int n_in,
                              void* d_out, int out_size, void* d_ws, size_t ws_size,
                              hipStream_t stream) {
    const float* x     = (const float*)d_in[0];
    const float* A     = (const float*)d_in[1];
    const float* alpha = (const float*)d_in[2];
    const float* w1    = (const float*)d_in[3];
    const float* b1    = (const float*)d_in[4];
    const float* w2    = (const float*)d_in[5];
    const float* b2    = (const float*)d_in[6];
    const float* w5    = (const float*)d_in[7];
    const float* b5    = (const float*)d_in[8];
    const float* w3    = (const float*)d_in[9];
    const float* b3    = (const float*)d_in[10];
    const float* w4    = (const float*)d_in[11];
    const float* b4    = (const float*)d_in[12];
    const float* g_w   = (const float*)d_in[13];
    const float* g_b   = (const float*)d_in[14];
    const float* a_w   = (const float*)d_in[15];
    const float* a_b   = (const float*)d_in[16];
    const float* bn_g  = (const float*)d_in[17];
    const float* bn_b  = (const float*)d_in[18];
    const float* bn_rm = (const float*)d_in[19];
    const float* bn_rv = (const float*)d_in[20];
    const float* rf_bw = (const float*)d_in[21];
    float* out = (float*)d_out;
    float* ws  = (float*)d_ws;

    float* x3    = ws;                          // 3,276,800
    float* x12p  = x3 + 3276800;                // 512,000 (=128*10*2*200)
    float* ppool = x12p + 512000;               // 131,072
    float* rf    = ppool + 131072;              // 131,072
    float* rel2  = rf + 131072;                 // 5,120,000

    hipMemsetAsync(ppool, 0, (size_t)131072 * sizeof(float), stream);
    hipLaunchKernelGGL(kA, dim3(N_ * 10), dim3(320), 0, stream,
                       x, w5, b5, w1, w2, x3, x12p, ppool);
    hipLaunchKernelGGL(k2_rel, dim3(N_, 4), dim3(256), 0, stream,
                       x12p, b1, b2, w4, b4, A, alpha, rel2);
    hipLaunchKernelGGL(k4_route, dim3(N_), dim3(256), 0, stream,
                       ppool, g_w, g_b, a_w, a_b, bn_g, bn_b, bn_rm, bn_rv, rf_bw, rf);
    hipLaunchKernelGGL(k5_out, dim3(N_ * 32), dim3(256), 0, stream,
                       x3, rf, rel2, w3, b3, out);
}

// Round 3
// 359.298 us; speedup vs baseline: 1.2976x; 1.2976x over previous
//
#include <hip/hip_runtime.h>

#define N_ 128
#define C_ 64
#define O_ 64
#define R_ 8
#define T_ 128
#define V_ 25
#define TV_ 3200   // T_*V_
#define EPS_ 1e-5f
#define G_ 4       // c-group per block in k5

// ---------------- K1: S[n,i,v] = sum_t x[n,i,t,v] ----------------
__global__ __launch_bounds__(256) void k1_colsum(const float* __restrict__ x,
                                                 float* __restrict__ S) {
    int ni = blockIdx.x;                       // n*C_ + i
    const float* xp = x + (size_t)ni * TV_;
    int tid = threadIdx.x;
    __shared__ float part[200];
    if (tid < 200) {
        float s = 0.f;
        #pragma unroll
        for (int k = 0; k < 16; ++k) s += xp[tid + 200 * k];
        part[tid] = s;                          // part[g*25+v], t = g + 8k
    }
    __syncthreads();
    if (tid < V_) {
        float t = 0.f;
        #pragma unroll
        for (int g = 0; g < 8; ++g) t += part[g * 25 + tid];
        S[ni * V_ + tid] = t;
    }
}

// ---------------- K3: x3[n,r,t,v] = sum_i w5[r,i]*x[n,i,t,v] + b5[r] ----------------
__global__ __launch_bounds__(256) void k3_x3(const float* __restrict__ x,
        const float* __restrict__ w5, const float* __restrict__ b5,
        float* __restrict__ x3) {
    __shared__ float w5s[R_ * C_];
    int tid = threadIdx.x;
    w5s[tid] = w5[tid];
    w5s[tid + 256] = w5[tid + 256];
    __syncthreads();
    int gid = blockIdx.x * 256 + tid;          // grid = 409600/256 = 1600 exact
    int n = gid / TV_, p = gid % TV_;
    float acc[R_];
    #pragma unroll
    for (int r = 0; r < R_; ++r) acc[r] = b5[r];
    const float* xp = x + (size_t)n * C_ * TV_ + p;
    for (int i = 0; i < C_; ++i) {
        float xv = xp[(size_t)i * TV_];
        #pragma unroll
        for (int r = 0; r < R_; ++r) acc[r] += w5s[r * C_ + i] * xv;
    }
    float* x3p = x3 + (size_t)n * R_ * TV_ + p;
    #pragma unroll
    for (int r = 0; r < R_; ++r) x3p[(size_t)r * TV_] = acc[r];
}

// ---------------- KP: ppool[n,r,t] = sum_v x3[n,r,t,v] ----------------
__global__ __launch_bounds__(256) void kP_pool(const float* __restrict__ x3,
                                               float* __restrict__ ppool) {
    int nr = blockIdx.x;                       // n*R_ + r
    int tid = threadIdx.x;
    __shared__ float buf[TV_];
    const float* xp = x3 + (size_t)nr * TV_;
    for (int idx = tid; idx < TV_; idx += 256) buf[idx] = xp[idx];
    __syncthreads();
    if (tid < T_) {
        float s = 0.f;
        #pragma unroll
        for (int v = 0; v < V_; ++v) s += buf[tid * V_ + v];
        ppool[(size_t)nr * T_ + tid] = s;       // raw sum; k4 scales by 1/V
    }
}

// ---------------- K2: S -> x1,x2 -> rel2[n,o,u,v] ----------------
// grid (N, 4), block 256; each block does 16 output channels.
__global__ __launch_bounds__(256) void k2_rel(const float* __restrict__ S,
        const float* __restrict__ w1, const float* __restrict__ b1,
        const float* __restrict__ w2, const float* __restrict__ b2,
        const float* __restrict__ w4, const float* __restrict__ b4,
        const float* __restrict__ A, const float* __restrict__ alpha,
        float* __restrict__ rel2) {
    int n = blockIdx.x, og = blockIdx.y;
    int c0 = og * 16;
    int tid = threadIdx.x;
    __shared__ float x1s[R_ * V_];
    __shared__ float x2s[R_ * V_];
    __shared__ float rels[R_ * 625];
    const float invT = 1.0f / (float)T_;
    for (int idx = tid; idx < 2 * R_ * V_; idx += 256) {
        int s = idx / (R_ * V_), rv = idx % (R_ * V_);
        int r = rv / V_, v = rv % V_;
        const float* w = s ? w2 : w1;
        float a = 0.f;
        for (int i = 0; i < C_; ++i) a += w[r * C_ + i] * S[(n * C_ + i) * V_ + v];
        a = a * invT + (s ? b2[r] : b1[r]);
        (s ? x2s : x1s)[rv] = a;
    }
    __syncthreads();
    for (int idx = tid; idx < R_ * 625; idx += 256) {
        int r = idx / 625, uv = idx % 625;
        rels[idx] = tanhf(x1s[r * V_ + uv / V_] - x2s[r * V_ + uv % V_]);
    }
    __syncthreads();
    float al = alpha[0];
    for (int idx = tid; idx < 16 * 625; idx += 256) {
        int o = c0 + idx / 625, uv = idx % 625;
        float acc = b4[o];
        #pragma unroll
        for (int r = 0; r < R_; ++r) acc += w4[o * R_ + r] * rels[r * 625 + uv];
        rel2[((size_t)n * O_ + o) * 625 + uv] = acc * al + A[uv];
    }
}

// ---------------- K4: RouteFuncMLP -> rf[n,r,t] (reads pooled tensor) ----------------
__global__ __launch_bounds__(256) void k4_route(const float* __restrict__ ppool,
        const float* __restrict__ g_w, const float* __restrict__ g_b,
        const float* __restrict__ a_w, const float* __restrict__ a_b,
        const float* __restrict__ bn_g, const float* __restrict__ bn_b,
        const float* __restrict__ bn_rm, const float* __restrict__ bn_rv,
        const float* __restrict__ rf_bw, float* __restrict__ rf) {
    int n = blockIdx.x, tid = threadIdx.x;
    __shared__ float ps[R_][T_];
    __shared__ float hs[R_][T_];
    __shared__ float gs[R_];
    __shared__ float ggs[R_];
    for (int idx = tid; idx < R_ * T_; idx += 256)
        ps[idx / T_][idx % T_] = ppool[(size_t)n * R_ * T_ + idx] * (1.0f / V_);
    __syncthreads();
    if (tid < R_) {
        float s = 0.f;
        for (int t = 0; t < T_; ++t) s += ps[tid][t];
        gs[tid] = s * (1.0f / T_);
    }
    __syncthreads();
    if (tid < R_) {
        float a = g_b[tid];
        #pragma unroll
        for (int i = 0; i < R_; ++i) a += g_w[tid * R_ + i] * gs[i];
        ggs[tid] = a;
    }
    __syncthreads();
    for (int idx = tid; idx < R_ * T_; idx += 256) {
        int r = idx / T_, t = idx % T_;
        float acc = a_b[r];
        #pragma unroll
        for (int i = 0; i < R_; ++i) {
            #pragma unroll
            for (int k = 0; k < 3; ++k) {
                int tt = t + k - 1;
                if (tt >= 0 && tt < T_)
                    acc += a_w[(r * R_ + i) * 3 + k] * (ps[i][tt] + ggs[i]);
            }
        }
        float sc = bn_g[r] * rsqrtf(bn_rv[r] + EPS_);
        float h = (acc - bn_rm[r]) * sc + bn_b[r];
        hs[r][t] = fmaxf(h, 0.f);
    }
    __syncthreads();
    for (int idx = tid; idx < R_ * T_; idx += 256) {
        int r = idx / T_, t = idx % T_;
        float acc = 1.0f;
        #pragma unroll
        for (int i = 0; i < R_; ++i) {
            #pragma unroll
            for (int k = 0; k < 3; ++k) {
                int tt = t + k - 1;
                if (tt >= 0 && tt < T_)
                    acc += rf_bw[(r * R_ + i) * 3 + k] * hs[i][tt];
            }
        }
        rf[((size_t)n * R_ + r) * T_ + t] = acc;
    }
}

// ---------------- K5: out[n,c,t,u] = sum_v rel2[n,c,u,v] * z[n,c,t,v] ----------------
// grid N*16*2 (c-group of 4, t-half), block 256.
__global__ __launch_bounds__(256) void k5_out(const float* __restrict__ x3,
        const float* __restrict__ rf, const float* __restrict__ rel2,
        const float* __restrict__ w3, const float* __restrict__ b3,
        float* __restrict__ out) {
    int b = blockIdx.x;
    int n = b / 32;
    int rem = b % 32;
    int cg = rem / 2, th = rem % 2;
    int c0 = cg * G_;
    int tid = threadIdx.x;
    __shared__ float rfs[R_][T_ / 2];          // 2 KB
    __shared__ float zs[G_][1600];             // 25.6 KB
    __shared__ float rels[G_][625];            // 10 KB
    for (int idx = tid; idx < R_ * (T_ / 2); idx += 256) {
        int r = idx / (T_ / 2), tt = idx % (T_ / 2);
        rfs[r][tt] = rf[((size_t)n * R_ + r) * T_ + th * (T_ / 2) + tt];
    }
    for (int idx = tid; idx < G_ * 625; idx += 256)
        rels[idx / 625][idx % 625] = rel2[((size_t)n * O_ + c0 + idx / 625) * 625 + idx % 625];
    float w3s[G_][R_], b3s[G_];
    #pragma unroll
    for (int cl = 0; cl < G_; ++cl) {
        b3s[cl] = b3[c0 + cl];
        #pragma unroll
        for (int r = 0; r < R_; ++r) w3s[cl][r] = w3[(c0 + cl) * R_ + r];
    }
    __syncthreads();
    // phase A: z for this (c-group, t-half)
    const float* x3p = x3 + (size_t)n * R_ * TV_ + th * 1600;
    for (int p = tid; p < 1600; p += 256) {
        int t = p / V_;
        float xv[R_];
        #pragma unroll
        for (int r = 0; r < R_; ++r) xv[r] = x3p[(size_t)r * TV_ + p] * rfs[r][t];
        #pragma unroll
        for (int cl = 0; cl < G_; ++cl) {
            float acc = b3s[cl];
            #pragma unroll
            for (int r = 0; r < R_; ++r) acc += w3s[cl][r] * xv[r];
            zs[cl][p] = acc;
        }
    }
    __syncthreads();
    // phase B: idx=(t,u), all 256 threads, coalesced stores
    float* op = out + (((size_t)n * O_ + c0) * T_ + th * (T_ / 2)) * V_;
    for (int cl = 0; cl < G_; ++cl) {
        const float* zrow = zs[cl];
        const float* rrow = rels[cl];
        for (int idx = tid; idx < 1600; idx += 256) {
            int t = idx / V_, u = idx % V_;
            float acc = 0.f;
            #pragma unroll
            for (int v = 0; v < V_; ++v) acc += zrow[t * V_ + v] * rrow[u * V_ + v];
            op[(size_t)cl * T_ * V_ + idx] = acc;
        }
    }
}

extern "C" void kernel_launch(void* const* d_in, const int* in_sizes, int n_in,
                              void* d_out, int out_size, void* d_ws, size_t ws_size,
                              hipStream_t stream) {
    const float* x     = (const float*)d_in[0];
    const float* A     = (const float*)d_in[1];
    const float* alpha = (const float*)d_in[2];
    const float* w1    = (const float*)d_in[3];
    const float* b1    = (const float*)d_in[4];
    const float* w2    = (const float*)d_in[5];
    const float* b2    = (const float*)d_in[6];
    const float* w5    = (const float*)d_in[7];
    const float* b5    = (const float*)d_in[8];
    const float* w3    = (const float*)d_in[9];
    const float* b3    = (const float*)d_in[10];
    const float* w4    = (const float*)d_in[11];
    const float* b4    = (const float*)d_in[12];
    const float* g_w   = (const float*)d_in[13];
    const float* g_b   = (const float*)d_in[14];
    const float* a_w   = (const float*)d_in[15];
    const float* a_b   = (const float*)d_in[16];
    const float* bn_g  = (const float*)d_in[17];
    const float* bn_b  = (const float*)d_in[18];
    const float* bn_rm = (const float*)d_in[19];
    const float* bn_rv = (const float*)d_in[20];
    const float* rf_bw = (const float*)d_in[21];
    float* out = (float*)d_out;
    float* ws  = (float*)d_ws;

    float* S     = ws;                          // 204,800
    float* x3    = S + 204800;                  // 3,276,800
    float* ppool = x3 + 3276800;                // 131,072
    float* rf    = ppool + 131072;              // 131,072
    float* rel2  = rf + 131072;                 // 5,120,000

    hipLaunchKernelGGL(k1_colsum, dim3(N_ * C_), dim3(256), 0, stream, x, S);
    hipLaunchKernelGGL(k3_x3, dim3(1600), dim3(256), 0, stream, x, w5, b5, x3);
    hipLaunchKernelGGL(kP_pool, dim3(N_ * R_), dim3(256), 0, stream, x3, ppool);
    hipLaunchKernelGGL(k2_rel, dim3(N_, 4), dim3(256), 0, stream,
                       S, w1, b1, w2, b2, w4, b4, A, alpha, rel2);
    hipLaunchKernelGGL(k4_route, dim3(N_), dim3(256), 0, stream,
                       ppool, g_w, g_b, a_w, a_b, bn_g, bn_b, bn_rm, bn_rv, rf_bw, rf);
    hipLaunchKernelGGL(k5_out, dim3(N_ * 32), dim3(256), 0, stream,
                       x3, rf, rel2, w3, b3, out);
}

// Round 4
// 322.745 us; speedup vs baseline: 1.4446x; 1.1133x over previous
//
#include <hip/hip_runtime.h>

#define N_ 128
#define C_ 64
#define O_ 64
#define R_ 8
#define T_ 128
#define V_ 25
#define TV_ 3200   // T_*V_
#define EPS_ 1e-5f
#define G_ 8       // c-group per block in k5

// ---------------- K1: S[n,i,v] = sum_t x[n,i,t,v] ----------------
__global__ __launch_bounds__(256) void k1_colsum(const float* __restrict__ x,
                                                 float* __restrict__ S) {
    int ni = blockIdx.x;                       // n*C_ + i
    const float* xp = x + (size_t)ni * TV_;
    int tid = threadIdx.x;
    __shared__ float part[200];
    if (tid < 200) {
        float s = 0.f;
        #pragma unroll
        for (int k = 0; k < 16; ++k) s += xp[tid + 200 * k];
        part[tid] = s;                          // part[g*25+v], t = g + 8k
    }
    __syncthreads();
    if (tid < V_) {
        float t = 0.f;
        #pragma unroll
        for (int g = 0; g < 8; ++g) t += part[g * 25 + tid];
        S[ni * V_ + tid] = t;
    }
}

// ---------------- K3: x3[n,r,t,v] = sum_i w5[r,i]*x[n,i,t,v] + b5[r] ----------------
// w5/b5 accessed with wave-uniform indices -> scalar (s_load) path, no LDS.
__global__ __launch_bounds__(256) void k3_x3(const float* __restrict__ x,
        const float* __restrict__ w5, const float* __restrict__ b5,
        float* __restrict__ x3) {
    int gid = blockIdx.x * 256 + threadIdx.x;  // grid = 409600/256 = 1600 exact
    int n = gid / TV_, p = gid % TV_;
    float acc[R_];
    #pragma unroll
    for (int r = 0; r < R_; ++r) acc[r] = b5[r];
    const float* xp = x + (size_t)n * C_ * TV_ + p;
    #pragma unroll
    for (int i = 0; i < C_; ++i) {
        float xv = xp[(size_t)i * TV_];
        #pragma unroll
        for (int r = 0; r < R_; ++r) acc[r] += w5[r * C_ + i] * xv;
    }
    float* x3p = x3 + (size_t)n * R_ * TV_ + p;
    #pragma unroll
    for (int r = 0; r < R_; ++r) x3p[(size_t)r * TV_] = acc[r];
}

// ---------------- K2: S -> x1,x2 -> rel2[n,o,u,v] ----------------
__global__ __launch_bounds__(256) void k2_rel(const float* __restrict__ S,
        const float* __restrict__ w1, const float* __restrict__ b1,
        const float* __restrict__ w2, const float* __restrict__ b2,
        const float* __restrict__ w4, const float* __restrict__ b4,
        const float* __restrict__ A, const float* __restrict__ alpha,
        float* __restrict__ rel2) {
    int n = blockIdx.x, og = blockIdx.y;
    int c0 = og * 16;
    int tid = threadIdx.x;
    __shared__ float x1s[R_ * V_];
    __shared__ float x2s[R_ * V_];
    __shared__ float rels[R_ * 625];
    const float invT = 1.0f / (float)T_;
    for (int idx = tid; idx < 2 * R_ * V_; idx += 256) {
        int s = idx / (R_ * V_), rv = idx % (R_ * V_);
        int r = rv / V_, v = rv % V_;
        const float* w = s ? w2 : w1;
        float a = 0.f;
        for (int i = 0; i < C_; ++i) a += w[r * C_ + i] * S[(n * C_ + i) * V_ + v];
        a = a * invT + (s ? b2[r] : b1[r]);
        (s ? x2s : x1s)[rv] = a;
    }
    __syncthreads();
    for (int idx = tid; idx < R_ * 625; idx += 256) {
        int r = idx / 625, uv = idx % 625;
        rels[idx] = tanhf(x1s[r * V_ + uv / V_] - x2s[r * V_ + uv % V_]);
    }
    __syncthreads();
    float al = alpha[0];
    for (int idx = tid; idx < 16 * 625; idx += 256) {
        int o = c0 + idx / 625, uv = idx % 625;
        float acc = b4[o];
        #pragma unroll
        for (int r = 0; r < R_; ++r) acc += w4[o * R_ + r] * rels[r * 625 + uv];
        rel2[((size_t)n * O_ + o) * 625 + uv] = acc * al + A[uv];
    }
}

// ---------------- K4: RouteFuncMLP -> rf[n,r,t] (pool fused, reads x3) ----------------
__global__ __launch_bounds__(256) void k4_route(const float* __restrict__ x3,
        const float* __restrict__ g_w, const float* __restrict__ g_b,
        const float* __restrict__ a_w, const float* __restrict__ a_b,
        const float* __restrict__ bn_g, const float* __restrict__ bn_b,
        const float* __restrict__ bn_rm, const float* __restrict__ bn_rv,
        const float* __restrict__ rf_bw, float* __restrict__ rf) {
    int n = blockIdx.x, tid = threadIdx.x;
    __shared__ float ps[R_][T_];
    __shared__ float hs[R_][T_];
    __shared__ float gs[R_];
    __shared__ float ggs[R_];
    for (int idx = tid; idx < R_ * T_; idx += 256) {
        int r = idx / T_, t = idx % T_;
        const float* xp = x3 + ((size_t)n * R_ + r) * TV_ + t * V_;
        float s = 0.f;
        #pragma unroll
        for (int v = 0; v < V_; ++v) s += xp[v];
        ps[r][t] = s * (1.0f / V_);
    }
    __syncthreads();
    if (tid < R_) {
        float s = 0.f;
        for (int t = 0; t < T_; ++t) s += ps[tid][t];
        gs[tid] = s * (1.0f / T_);
    }
    __syncthreads();
    if (tid < R_) {
        float a = g_b[tid];
        #pragma unroll
        for (int i = 0; i < R_; ++i) a += g_w[tid * R_ + i] * gs[i];
        ggs[tid] = a;
    }
    __syncthreads();
    for (int idx = tid; idx < R_ * T_; idx += 256) {
        int r = idx / T_, t = idx % T_;
        float acc = a_b[r];
        #pragma unroll
        for (int i = 0; i < R_; ++i) {
            #pragma unroll
            for (int k = 0; k < 3; ++k) {
                int tt = t + k - 1;
                if (tt >= 0 && tt < T_)
                    acc += a_w[(r * R_ + i) * 3 + k] * (ps[i][tt] + ggs[i]);
            }
        }
        float sc = bn_g[r] * rsqrtf(bn_rv[r] + EPS_);
        float h = (acc - bn_rm[r]) * sc + bn_b[r];
        hs[r][t] = fmaxf(h, 0.f);
    }
    __syncthreads();
    for (int idx = tid; idx < R_ * T_; idx += 256) {
        int r = idx / T_, t = idx % T_;
        float acc = 1.0f;
        #pragma unroll
        for (int i = 0; i < R_; ++i) {
            #pragma unroll
            for (int k = 0; k < 3; ++k) {
                int tt = t + k - 1;
                if (tt >= 0 && tt < T_)
                    acc += rf_bw[(r * R_ + i) * 3 + k] * hs[i][tt];
            }
        }
        rf[((size_t)n * R_ + r) * T_ + t] = acc;
    }
}

// ---------------- K5: out[n,c,t,u] = sum_v rel2[n,c,u,v] * z[n,c,t,v] ----------------
// grid N*8*2 (c-group of 8, t-half), block 512 (8 waves; wave = one channel).
__global__ __launch_bounds__(512) void k5_out(const float* __restrict__ x3,
        const float* __restrict__ rf, const float* __restrict__ rel2,
        const float* __restrict__ w3, const float* __restrict__ b3,
        float* __restrict__ out) {
    int b = blockIdx.x;
    int n = b / 16;
    int rem = b % 16;
    int cg = rem / 2, th = rem % 2;
    int c0 = cg * G_;
    int tid = threadIdx.x;
    __shared__ float rfs[R_][64];              // 2 KB
    __shared__ float zs[G_][1600];             // 51.2 KB
    __shared__ float rels[G_][V_][28];         // 22.4 KB (padded rows, 16B-aligned)
    // stage rf (this t-half)
    if (tid < R_ * 64) {
        int r = tid / 64, tl = tid % 64;
        rfs[r][tl] = rf[((size_t)n * R_ + r) * T_ + th * 64 + tl];
    }
    // stage rel rows
    for (int idx = tid; idx < G_ * 625; idx += 512) {
        int cl = idx / 625, uv = idx % 625;
        rels[cl][uv / 25][uv % 25] = rel2[((size_t)n * O_ + c0 + cl) * 625 + uv];
    }
    __syncthreads();
    // phase A: z for this (c-group, t-half); w3/b3 via scalar path
    const float* x3p = x3 + (size_t)n * R_ * TV_ + th * 1600;
    for (int p = tid; p < 1600; p += 512) {
        int t = p / V_;
        float y[R_];
        #pragma unroll
        for (int r = 0; r < R_; ++r) y[r] = x3p[(size_t)r * TV_ + p] * rfs[r][t];
        #pragma unroll
        for (int cl = 0; cl < G_; ++cl) {
            float a = b3[c0 + cl];
            #pragma unroll
            for (int r = 0; r < R_; ++r) a += w3[(c0 + cl) * R_ + r] * y[r];
            zs[cl][p] = a;
        }
    }
    __syncthreads();
    // phase B: wave = channel cl, lane = t-row; z row in VGPRs, rel broadcast f4
    {
        int cl = tid >> 6, tl = tid & 63;
        float zreg[V_];
        #pragma unroll
        for (int v = 0; v < V_; ++v) zreg[v] = zs[cl][tl * V_ + v];
        float accu[V_];
        #pragma unroll
        for (int u = 0; u < V_; ++u) {
            const float4* rp4 = (const float4*)&rels[cl][u][0];
            float4 a0 = rp4[0], a1 = rp4[1], a2 = rp4[2];
            float4 a3 = rp4[3], a4 = rp4[4], a5 = rp4[5];
            float acc = zreg[24] * rels[cl][u][24];
            acc += zreg[0] * a0.x + zreg[1] * a0.y + zreg[2] * a0.z + zreg[3] * a0.w;
            acc += zreg[4] * a1.x + zreg[5] * a1.y + zreg[6] * a1.z + zreg[7] * a1.w;
            acc += zreg[8] * a2.x + zreg[9] * a2.y + zreg[10] * a2.z + zreg[11] * a2.w;
            acc += zreg[12] * a3.x + zreg[13] * a3.y + zreg[14] * a3.z + zreg[15] * a3.w;
            acc += zreg[16] * a4.x + zreg[17] * a4.y + zreg[18] * a4.z + zreg[19] * a4.w;
            acc += zreg[20] * a5.x + zreg[21] * a5.y + zreg[22] * a5.z + zreg[23] * a5.w;
            accu[u] = acc;
        }
        // write results back into own zs slot (thread-private range)
        #pragma unroll
        for (int u = 0; u < V_; ++u) zs[cl][tl * V_ + u] = accu[u];
    }
    __syncthreads();
    // coalesced copy-out
    size_t ob = (((size_t)n * O_ + c0) * T_ + th * 64) * V_;
    const float* zf = &zs[0][0];
    for (int j = tid; j < G_ * 1600; j += 512) {
        int cl = j / 1600, rest = j % 1600;
        out[ob + (size_t)cl * (T_ * V_) + rest] = zf[j];
    }
}

extern "C" void kernel_launch(void* const* d_in, const int* in_sizes, int n_in,
                              void* d_out, int out_size, void* d_ws, size_t ws_size,
                              hipStream_t stream) {
    const float* x     = (const float*)d_in[0];
    const float* A     = (const float*)d_in[1];
    const float* alpha = (const float*)d_in[2];
    const float* w1    = (const float*)d_in[3];
    const float* b1    = (const float*)d_in[4];
    const float* w2    = (const float*)d_in[5];
    const float* b2    = (const float*)d_in[6];
    const float* w5    = (const float*)d_in[7];
    const float* b5    = (const float*)d_in[8];
    const float* w3    = (const float*)d_in[9];
    const float* b3    = (const float*)d_in[10];
    const float* w4    = (const float*)d_in[11];
    const float* b4    = (const float*)d_in[12];
    const float* g_w   = (const float*)d_in[13];
    const float* g_b   = (const float*)d_in[14];
    const float* a_w   = (const float*)d_in[15];
    const float* a_b   = (const float*)d_in[16];
    const float* bn_g  = (const float*)d_in[17];
    const float* bn_b  = (const float*)d_in[18];
    const float* bn_rm = (const float*)d_in[19];
    const float* bn_rv = (const float*)d_in[20];
    const float* rf_bw = (const float*)d_in[21];
    float* out = (float*)d_out;
    float* ws  = (float*)d_ws;

    float* S     = ws;                          // 204,800
    float* x3    = S + 204800;                  // 3,276,800
    float* rf    = x3 + 3276800;                // 131,072
    float* rel2  = rf + 131072;                 // 5,120,000

    hipLaunchKernelGGL(k1_colsum, dim3(N_ * C_), dim3(256), 0, stream, x, S);
    hipLaunchKernelGGL(k3_x3, dim3(1600), dim3(256), 0, stream, x, w5, b5, x3);
    hipLaunchKernelGGL(k2_rel, dim3(N_, 4), dim3(256), 0, stream,
                       S, w1, b1, w2, b2, w4, b4, A, alpha, rel2);
    hipLaunchKernelGGL(k4_route, dim3(N_), dim3(256), 0, stream,
                       x3, g_w, g_b, a_w, a_b, bn_g, bn_b, bn_rm, bn_rv, rf_bw, rf);
    hipLaunchKernelGGL(k5_out, dim3(N_ * 16), dim3(512), 0, stream,
                       x3, rf, rel2, w3, b3, out);
}

// Round 7
// 317.954 us; speedup vs baseline: 1.4664x; 1.0151x over previous
//
#include <hip/hip_runtime.h>

#define N_ 128
#define C_ 64
#define O_ 64
#define R_ 8
#define T_ 128
#define V_ 25
#define TV_ 3200   // T_*V_
#define EPS_ 1e-5f
#define G_ 8       // c-group per block in k5

// ---------------- K1: S[n,i,v] = sum_t x[n,i,t,v] ----------------
__global__ __launch_bounds__(256) void k1_colsum(const float* __restrict__ x,
                                                 float* __restrict__ S) {
    int ni = blockIdx.x;                       // n*C_ + i
    const float* xp = x + (size_t)ni * TV_;
    int tid = threadIdx.x;
    __shared__ float part[200];
    if (tid < 200) {
        float s = 0.f;
        #pragma unroll
        for (int k = 0; k < 16; ++k) s += xp[tid + 200 * k];
        part[tid] = s;                          // part[g*25+v], t = g + 8k
    }
    __syncthreads();
    if (tid < V_) {
        float t = 0.f;
        #pragma unroll
        for (int g = 0; g < 8; ++g) t += part[g * 25 + tid];
        S[ni * V_ + tid] = t;
    }
}

// ---------------- K3: x3[n,r,t,v] = sum_i w5[r,i]*x[n,i,t,v] + b5[r] ----------------
__global__ __launch_bounds__(256) void k3_x3(const float* __restrict__ x,
        const float* __restrict__ w5, const float* __restrict__ b5,
        float* __restrict__ x3) {
    int gid = blockIdx.x * 256 + threadIdx.x;  // grid = 409600/256 = 1600 exact
    int n = gid / TV_, p = gid % TV_;
    float acc[R_];
    #pragma unroll
    for (int r = 0; r < R_; ++r) acc[r] = b5[r];
    const float* xp = x + (size_t)n * C_ * TV_ + p;
    #pragma unroll
    for (int i = 0; i < C_; ++i) {
        float xv = xp[(size_t)i * TV_];
        #pragma unroll
        for (int r = 0; r < R_; ++r) acc[r] += w5[r * C_ + i] * xv;
    }
    float* x3p = x3 + (size_t)n * R_ * TV_ + p;
    #pragma unroll
    for (int r = 0; r < R_; ++r) x3p[(size_t)r * TV_] = acc[r];
}

// ---------------- K2: S -> x1,x2 -> rel2[n,o,u,v] ----------------
__global__ __launch_bounds__(256) void k2_rel(const float* __restrict__ S,
        const float* __restrict__ w1, const float* __restrict__ b1,
        const float* __restrict__ w2, const float* __restrict__ b2,
        const float* __restrict__ w4, const float* __restrict__ b4,
        const float* __restrict__ A, const float* __restrict__ alpha,
        float* __restrict__ rel2) {
    int n = blockIdx.x, og = blockIdx.y;
    int c0 = og * 16;
    int tid = threadIdx.x;
    __shared__ float x1s[R_ * V_];
    __shared__ float x2s[R_ * V_];
    __shared__ float rels[R_ * 625];
    const float invT = 1.0f / (float)T_;
    for (int idx = tid; idx < 2 * R_ * V_; idx += 256) {
        int s = idx / (R_ * V_), rv = idx % (R_ * V_);
        int r = rv / V_, v = rv % V_;
        const float* w = s ? w2 : w1;
        float a = 0.f;
        for (int i = 0; i < C_; ++i) a += w[r * C_ + i] * S[(n * C_ + i) * V_ + v];
        a = a * invT + (s ? b2[r] : b1[r]);
        (s ? x2s : x1s)[rv] = a;
    }
    __syncthreads();
    for (int idx = tid; idx < R_ * 625; idx += 256) {
        int r = idx / 625, uv = idx % 625;
        rels[idx] = tanhf(x1s[r * V_ + uv / V_] - x2s[r * V_ + uv % V_]);
    }
    __syncthreads();
    float al = alpha[0];
    for (int idx = tid; idx < 16 * 625; idx += 256) {
        int o = c0 + idx / 625, uv = idx % 625;
        float acc = b4[o];
        #pragma unroll
        for (int r = 0; r < R_; ++r) acc += w4[o * R_ + r] * rels[r * 625 + uv];
        rel2[((size_t)n * O_ + o) * 625 + uv] = acc * al + A[uv];
    }
}

// ---------------- KP: ppool[n,r,t] = sum_v x3[n,r,t,v] (raw sum) ----------------
__global__ __launch_bounds__(256) void kP_pool(const float* __restrict__ x3,
                                               float* __restrict__ ppool) {
    int nr = blockIdx.x;                       // n*R_ + r
    int tid = threadIdx.x;
    __shared__ float buf[TV_];
    const float* xp = x3 + (size_t)nr * TV_;
    for (int idx = tid; idx < TV_; idx += 256) buf[idx] = xp[idx];
    __syncthreads();
    if (tid < T_) {
        float s = 0.f;
        #pragma unroll
        for (int v = 0; v < V_; ++v) s += buf[tid * V_ + v];
        ppool[(size_t)nr * T_ + tid] = s;
    }
}

// ---------------- K4b: RouteFuncMLP conv chain -> rf[n,r,t] ----------------
// grid (N_, 2): t-half per block; full ps (4 KB) kept in LDS, halo recomputed.
// h(t) stored at hs[r][t - t0 + 2]; rf at t reads hs[r][j+k+1] (tt = t+k-1).
__global__ __launch_bounds__(256) void k4b_route(const float* __restrict__ ppool,
        const float* __restrict__ g_w, const float* __restrict__ g_b,
        const float* __restrict__ a_w, const float* __restrict__ a_b,
        const float* __restrict__ bn_g, const float* __restrict__ bn_b,
        const float* __restrict__ bn_rm, const float* __restrict__ bn_rv,
        const float* __restrict__ rf_bw, float* __restrict__ rf) {
    int n = blockIdx.x, th = blockIdx.y;
    int t0 = th * 64;
    int tid = threadIdx.x;
    __shared__ float ps[R_][T_];
    __shared__ float hs[R_][68];               // [0]=g stash, [1..66]=h(t0-1..t0+64)
    __shared__ float ggs[R_];
    for (int idx = tid; idx < R_ * T_; idx += 256)
        ps[idx / T_][idx % T_] = ppool[(size_t)n * R_ * T_ + idx] * (1.0f / V_);
    __syncthreads();
    if (tid < R_) {
        float s = 0.f;
        for (int t = 0; t < T_; ++t) s += ps[tid][t];
        hs[tid][0] = s * (1.0f / T_);          // temp stash g[r]
    }
    __syncthreads();
    if (tid < R_) {
        float a = g_b[tid];
        #pragma unroll
        for (int i = 0; i < R_; ++i) a += g_w[tid * R_ + i] * hs[i][0];
        ggs[tid] = a;
    }
    __syncthreads();
    // h for t in [t0-1, t0+64] (66 values; h(t) at hs[r][t-t0+2])
    for (int idx = tid; idx < R_ * 66; idx += 256) {
        int r = idx / 66, j = idx % 66;
        int t = t0 + j - 1;                    // [t0-1, t0+64]
        float h = 0.f;
        if (t >= 0 && t < T_) {
            float acc = a_b[r];
            #pragma unroll
            for (int i = 0; i < R_; ++i) {
                #pragma unroll
                for (int k = 0; k < 3; ++k) {
                    int tt = t + k - 1;
                    if (tt >= 0 && tt < T_)
                        acc += a_w[(r * R_ + i) * 3 + k] * (ps[i][tt] + ggs[i]);
                }
            }
            float sc = bn_g[r] * rsqrtf(bn_rv[r] + EPS_);
            h = fmaxf((acc - bn_rm[r]) * sc + bn_b[r], 0.f);
        }
        hs[r][j + 1] = h;                      // h(t) at index t-t0+2
    }
    __syncthreads();
    // rf for t in [t0, t0+63]: h(t+k-1) is at hs[i][j+k+1]
    for (int idx = tid; idx < R_ * 64; idx += 256) {
        int r = idx / 64, j = idx % 64;
        int t = t0 + j;
        float acc = 1.0f;
        #pragma unroll
        for (int i = 0; i < R_; ++i) {
            #pragma unroll
            for (int k = 0; k < 3; ++k) {
                int tt = t + k - 1;
                if (tt >= 0 && tt < T_)
                    acc += rf_bw[(r * R_ + i) * 3 + k] * hs[i][j + k + 1];
            }
        }
        rf[((size_t)n * R_ + r) * T_ + t] = acc;
    }
}

// ---------------- K5: out[n,c,t,u] = sum_v rel2[n,c,u,v] * z[n,c,t,v] ----------------
// grid N*8*2 (c-group of 8, t-half), block 512 (8 waves; wave = one channel).
// rel read via wave-uniform scalar loads (s_load), not LDS.
__global__ __launch_bounds__(512) void k5_out(const float* __restrict__ x3,
        const float* __restrict__ rf, const float* __restrict__ rel2,
        const float* __restrict__ w3, const float* __restrict__ b3,
        float* __restrict__ out) {
    int b = blockIdx.x;
    int n = b / 16;
    int rem = b % 16;
    int cg = rem / 2, th = rem % 2;
    int c0 = cg * G_;
    int tid = threadIdx.x;
    __shared__ float rfs[R_][64];              // 2 KB
    __shared__ __align__(16) float zs[G_][1600];  // 51.2 KB
    // stage rf (this t-half): exactly 512 entries
    {
        int r = tid / 64, tl = tid % 64;
        rfs[r][tl] = rf[((size_t)n * R_ + r) * T_ + th * 64 + tl];
    }
    __syncthreads();
    // phase A: z for this (c-group, t-half); w3/b3 via scalar path
    const float* x3p = x3 + (size_t)n * R_ * TV_ + th * 1600;
    for (int p = tid; p < 1600; p += 512) {
        int t = p / V_;
        float y[R_];
        #pragma unroll
        for (int r = 0; r < R_; ++r) y[r] = x3p[(size_t)r * TV_ + p] * rfs[r][t];
        #pragma unroll
        for (int cl = 0; cl < G_; ++cl) {
            float a = b3[c0 + cl];
            #pragma unroll
            for (int r = 0; r < R_; ++r) a += w3[(c0 + cl) * R_ + r] * y[r];
            zs[cl][p] = a;
        }
    }
    __syncthreads();
    // phase B: wave = channel cl (readfirstlane -> scalar rel loads), lane = t-row
    {
        int cl = __builtin_amdgcn_readfirstlane(tid >> 6);
        int tl = tid & 63;
        const float* relp = rel2 + ((size_t)n * O_ + c0 + cl) * 625;
        float zreg[V_];
        #pragma unroll
        for (int v = 0; v < V_; ++v) zreg[v] = zs[cl][tl * V_ + v];
        float accu[V_];
        #pragma unroll
        for (int u = 0; u < V_; ++u) {
            float acc = 0.f;
            #pragma unroll
            for (int j = 0; j < V_; ++j) acc += relp[u * V_ + j] * zreg[j];
            accu[u] = acc;
        }
        #pragma unroll
        for (int u = 0; u < V_; ++u) zs[cl][tl * V_ + u] = accu[u];
    }
    __syncthreads();
    // coalesced float4 copy-out: 12800 floats = 3200 float4
    size_t ob = (((size_t)n * O_ + c0) * T_ + th * 64) * V_;  // multiple of 1600
    float4* out4 = (float4*)(out + ob);
    const float4* zf4 = (const float4*)&zs[0][0];
    for (int j = tid; j < 3200; j += 512) {
        int cl = j / 400, r4 = j % 400;        // 400 f4 per cl-row of 1600 floats
        out4[(size_t)cl * 800 + r4] = zf4[j];  // out stride per c = 3200 floats
    }
}

extern "C" void kernel_launch(void* const* d_in, const int* in_sizes, int n_in,
                              void* d_out, int out_size, void* d_ws, size_t ws_size,
                              hipStream_t stream) {
    const float* x     = (const float*)d_in[0];
    const float* A     = (const float*)d_in[1];
    const float* alpha = (const float*)d_in[2];
    const float* w1    = (const float*)d_in[3];
    const float* b1    = (const float*)d_in[4];
    const float* w2    = (const float*)d_in[5];
    const float* b2    = (const float*)d_in[6];
    const float* w5    = (const float*)d_in[7];
    const float* b5    = (const float*)d_in[8];
    const float* w3    = (const float*)d_in[9];
    const float* b3    = (const float*)d_in[10];
    const float* w4    = (const float*)d_in[11];
    const float* b4    = (const float*)d_in[12];
    const float* g_w   = (const float*)d_in[13];
    const float* g_b   = (const float*)d_in[14];
    const float* a_w   = (const float*)d_in[15];
    const float* a_b   = (const float*)d_in[16];
    const float* bn_g  = (const float*)d_in[17];
    const float* bn_b  = (const float*)d_in[18];
    const float* bn_rm = (const float*)d_in[19];
    const float* bn_rv = (const float*)d_in[20];
    const float* rf_bw = (const float*)d_in[21];
    float* out = (float*)d_out;
    float* ws  = (float*)d_ws;

    float* S     = ws;                          // 204,800
    float* x3    = S + 204800;                  // 3,276,800
    float* ppool = x3 + 3276800;                // 131,072
    float* rf    = ppool + 131072;              // 131,072
    float* rel2  = rf + 131072;                 // 5,120,000

    hipLaunchKernelGGL(k1_colsum, dim3(N_ * C_), dim3(256), 0, stream, x, S);
    hipLaunchKernelGGL(k3_x3, dim3(1600), dim3(256), 0, stream, x, w5, b5, x3);
    hipLaunchKernelGGL(k2_rel, dim3(N_, 4), dim3(256), 0, stream,
                       S, w1, b1, w2, b2, w4, b4, A, alpha, rel2);
    hipLaunchKernelGGL(kP_pool, dim3(N_ * R_), dim3(256), 0, stream, x3, ppool);
    hipLaunchKernelGGL(k4b_route, dim3(N_, 2), dim3(256), 0, stream,
                       ppool, g_w, g_b, a_w, a_b, bn_g, bn_b, bn_rm, bn_rv, rf_bw, rf);
    hipLaunchKernelGGL(k5_out, dim3(N_ * 16), dim3(512), 0, stream,
                       x3, rf, rel2, w3, b3, out);
}